// Round 20
// baseline (156.597 us; speedup 1.0000x reference)
//
#include <hip/hip_runtime.h>
#include <math.h>

typedef __attribute__((ext_vector_type(8))) short s16x8;
typedef __attribute__((ext_vector_type(4))) float f32x4;
typedef __attribute__((ext_vector_type(2))) float f32x2;

#define LOG2E 1.4426950408889634f

// ---- workspace layout (float offsets) ----
#define OFF_XH   0           // xh bf16 NHWC [4][4096][256] = 2,097,152 floats
#define OFF_WB   2097152     // conv1 weights bf16 MFMA layout [ch2][ck8][tap9][g4][co64][j8]
#define OFF_PQT  2244608     // [ic16][part8][o128][4] = coalesced {A,B,P',D'}
#define OFF_W2   2310144     // W2cat [21][256] = [w2 | w2@base_w]
#define OFF_H    2315520     // h f32 NHWC [16384][128]

// ---------------- fused prologue: transpose x | prep weights | w2b ---------
__global__ __launch_bounds__(256) void prep_all_k(
    const float* __restrict__ x, const float* __restrict__ w1,
    const float* __restrict__ ks, const float* __restrict__ kt,
    const float* __restrict__ kw, const float* __restrict__ kb,
    const float* __restrict__ w2, float* __restrict__ ws) {
  int blk = blockIdx.x;
  int t = threadIdx.x;
  if (blk < 1024) {
    __shared__ float lsm[64][65];
    unsigned short* xh = (unsigned short*)(ws + OFF_XH);
    int pr = blk & 63, cib = (blk >> 6) & 3, bb = blk >> 8;
    int sp0 = pr * 64;
    const float* src = x + (unsigned)(bb * 256 + cib * 64) * 4096 + sp0;
#pragma unroll
    for (int rr = 0; rr < 16; ++rr) {
      int idx = rr * 256 + t;
      int ci = idx >> 6, px = idx & 63;
      lsm[ci][px] = src[ci * 4096 + px];
    }
    __syncthreads();
#pragma unroll
    for (int rr = 0; rr < 16; ++rr) {
      int idx = rr * 256 + t;
      int px = idx >> 6, ci = idx & 63;
      unsigned u = __float_as_uint(lsm[ci][px]);
      xh[(unsigned)(bb * 4096 + sp0 + px) * 256 + cib * 64 + ci] =
          (unsigned short)((u + 0x7FFF + ((u >> 16) & 1)) >> 16);
    }
  } else if (blk < 2251) {
    // KAN folding: contribution = fma(P',h,D') * exp2(h*fma(A,h,B));
    // A=Q, B=-2QT, P'=P0*2^C, D'=-P0*T*2^C, C=QT^2, Q=-0.5*log2e/s^2, P0=-kw/s.
    // Param layout coalesced: [ic][part8][o128][4f].
    int tid = (blk - 1024) * 256 + t;
    unsigned short* Wb = (unsigned short*)(ws + OFF_WB);
    if (tid < 294912) {
      int j = tid & 7, co = (tid >> 3) & 63, g = (tid >> 9) & 3, r = tid >> 11;
      int t9 = r % 9, q = r / 9, ck = q & 7, chh = q >> 3;
      int ci = ck * 32 + g * 8 + j, cog = chh * 64 + co;
      unsigned u = __float_as_uint(w1[(unsigned)(cog * 256 + ci) * 9 + t9]);
      Wb[tid] = (unsigned short)((u + 0x7FFF + ((u >> 16) & 1)) >> 16);
    } else if (tid < 294912 + 16384) {
      int i2 = tid - 294912;
      int i = i2 >> 7, o = i2 & 127;
      int ic = i >> 3, k = i & 7;
      float rs = 1.f / ks[o * 128 + i];
      float T  = kt[o * 128 + i];
      float A  = -0.7213475204444817f * rs * rs;   // Q
      float Bq = -2.f * A * T;
      float C  = A * T * T;
      float P0 = -rs * kw[o * 128 + i];
      float sc = exp2f(C);
      int khi = k >> 2, klo = k & 3;
      unsigned base = ((unsigned)ic * 8 * 128 + o) * 4 + klo;  // + part*512
      ws[OFF_PQT + base + (0 + khi) * 512] = A;
      ws[OFF_PQT + base + (2 + khi) * 512] = Bq;
      ws[OFF_PQT + base + (4 + khi) * 512] = P0 * sc;
      ws[OFF_PQT + base + (6 + khi) * 512] = -P0 * T * sc;
    } else if (tid < 294912 + 16384 + 2688) {
      int i3 = tid - 294912 - 16384;
      int nc = i3 >> 7, k = i3 & 127;
      ws[OFF_W2 + nc * 256 + k] = w2[nc * 128 + k];
    }
  } else {
    int nc = blk - 2251;
    if (t < 128) {
      float acc = 0.f;
      for (int o = 0; o < 128; ++o)
        acc = fmaf(w2[nc * 128 + o], kb[o * 128 + t], acc);
      ws[OFF_W2 + nc * 256 + 128 + t] = acc;
    }
  }
}

// ---------------- conv1 3x3 as bf16 MFMA implicit GEMM ---------------------
// r20 = r19's dbuf with the addressing bug fixed (r19 used a pointer-as-
// offset trick that doubled the A-stage offset -> corrupted buffers -> NaN).
// Block 128M(2y x 64x) x 64N, Mr=4/Nr=2; explicit A+B double-buffer (116KB,
// 1 block/CU): issue ck+1 loads -> compute ck (72 MFMAs hide the loads) ->
// write buf^1 -> ONE barrier per ck. grid 256 = bb(4) x yt(32) x ch(2).
__global__ __launch_bounds__(256) void conv1_mfma_k(
    const unsigned short* __restrict__ xh, const unsigned short* __restrict__ Wb,
    const float* __restrict__ b1, float* __restrict__ h) {
  __shared__ unsigned short Asm[2][4 * 66 * 40];  // 2 x 21.1KB
  __shared__ unsigned short Bsm[2][18432];        // 2 x 36.9KB  (total 116KB)
  int blk = blockIdx.x;
  int ch = blk & 1, yt = (blk >> 1) & 31, bb = blk >> 6;
  int y0 = yt * 2;
  int t = threadIdx.x;
  int wave = t >> 6, lane = t & 63;
  int wn = wave & 1, wm = wave >> 1;   // wm = output y-row within tile
  int l15 = lane & 15, lg = lane >> 4;

  if (t < 16) {  // zero x-halo columns in BOTH buffers (stay zero)
    int bf = t >> 3, r = (t >> 1) & 3, xl = (t & 1) * 65;
    float4 z = {0, 0, 0, 0};
    float4* p = (float4*)&Asm[bf][(r * 66 + xl) * 40];
    p[0] = z; p[1] = z; p[2] = z; p[3] = z; p[4] = z;
  }

  f32x4 acc[4][2];
  f32x4 zz = {0.f, 0.f, 0.f, 0.f};
#pragma unroll
  for (int f = 0; f < 4; ++f) { acc[f][0] = zz; acc[f][1] = zz; }

  int r_st = t >> 6, x_st = t & 63;    // 4 rows x 64 px staging map
  int gy = y0 - 1 + r_st;
  bool yok = (gy >= 0) & (gy < 64);
  const unsigned short* asrc = xh + (unsigned)(bb * 4096 + gy * 64 + x_st) * 256;
  int aoff = (r_st * 66 + x_st + 1) * 40;   // ELEMENT offset into Asm[buf]
  const unsigned short* bslab = Wb + ch * 8 * 18432;

  // prologue: stage ck 0 into buf 0
  float4 av0 = {0,0,0,0}, av1 = av0, av2 = av0, av3 = av0;
  float4 bv[9];
  if (yok) {
    const float4* s = (const float4*)(asrc);
    av0 = s[0]; av1 = s[1]; av2 = s[2]; av3 = s[3];
  }
  {
    const float4* s = (const float4*)(bslab);
#pragma unroll
    for (int j = 0; j < 9; ++j) bv[j] = s[j * 256 + t];
  }
  {
    float4* d = (float4*)&Asm[0][aoff];
    d[0] = av0; d[1] = av1; d[2] = av2; d[3] = av3;
    float4* db = (float4*)&Bsm[0][0];
#pragma unroll
    for (int j = 0; j < 9; ++j) db[j * 256 + t] = bv[j];
  }
  __syncthreads();

  for (int ck = 0; ck < 8; ++ck) {
    int cur = ck & 1;
    // issue next chunk's loads (latency hides under compute below)
    if (ck < 7) {
      av0 = (float4){0,0,0,0}; av1 = av0; av2 = av0; av3 = av0;
      if (yok) {
        const float4* s = (const float4*)(asrc + (ck + 1) * 32);
        av0 = s[0]; av1 = s[1]; av2 = s[2]; av3 = s[3];
      }
      const float4* s = (const float4*)(bslab + (ck + 1) * 18432);
#pragma unroll
      for (int j = 0; j < 9; ++j) bv[j] = s[j * 256 + t];
    }
    // compute ck from buf[cur]
    const unsigned short* As = &Asm[cur][0];
    const unsigned short* Bs = &Bsm[cur][0];
#pragma unroll
    for (int t9 = 0; t9 < 9; ++t9) {
      int ky = t9 / 3, kx = t9 % 3;
      s16x8 a[4], b[2];
      int abase = ((wm + ky) * 66 + l15 + kx) * 40 + lg * 8;
#pragma unroll
      for (int f = 0; f < 4; ++f)
        a[f] = *(const s16x8*)&As[abase + f * 640];
#pragma unroll
      for (int n = 0; n < 2; ++n)
        b[n] = *(const s16x8*)&Bs[((t9 * 4 + lg) * 64 + wn * 32 + n * 16 + l15) * 8];
#pragma unroll
      for (int f = 0; f < 4; ++f)
#pragma unroll
        for (int n = 0; n < 2; ++n)
          acc[f][n] = __builtin_amdgcn_mfma_f32_16x16x32_bf16(a[f], b[n], acc[f][n], 0, 0, 0);
    }
    // write next chunk into the other buffer
    if (ck < 7) {
      float4* d = (float4*)&Asm[cur ^ 1][aoff];
      d[0] = av0; d[1] = av1; d[2] = av2; d[3] = av3;
      float4* db = (float4*)&Bsm[cur ^ 1][0];
#pragma unroll
      for (int j = 0; j < 9; ++j) db[j * 256 + t] = bv[j];
    }
    __syncthreads();
  }
  // epilogue: bias + relu, store h NHWC f32
#pragma unroll
  for (int n = 0; n < 2; ++n) {
    int co = ch * 64 + wn * 32 + n * 16 + l15;
    float bz = b1[co];
#pragma unroll
    for (int f = 0; f < 4; ++f) {
      int xbase = f * 16 + lg * 4;
      float* dst = h + (unsigned)(bb * 4096 + (y0 + wm) * 64 + xbase) * 128 + co;
#pragma unroll
      for (int r = 0; r < 4; ++r) {
        float v = acc[f][n][r] + bz;
        dst[r * 128] = v > 0.f ? v : 0.f;
      }
    }
  }
}

// ---------------- Wav-KAN + fused conv2 (r17 structure + zero-skip) --------
// h is wave-uniform per (n,i) (LDS broadcast) and ~50% of h are exactly 0
// post-ReLU. At h==0 the contribution is exactly D' (exp2(0)=1): a wave-
// uniform scalar branch skips 3 pk + 2 exp per all-zero pair (p ~ 25%).
// Bit-exact with the full path.
__global__ __launch_bounds__(512) void wavkan_conv2_k(
    const float* __restrict__ h, const float* __restrict__ PQT,
    const float* __restrict__ w2c, const float* __restrict__ b2,
    float* __restrict__ out) {
  __shared__ float hsm[8][132];        // 4.2 KB
  __shared__ float red[3][2][8][64];   // 12 KB partial sums [ich-1][oh][n][lane]
  __shared__ float ksm[8][132];        // 4.2 KB k_wav rows
  int n0 = blockIdx.x * 8;
  int t = threadIdx.x;
  if (t < 256) {
    int row = t >> 5, c4 = (t & 31) * 4;
    *(float4*)&hsm[row][c4] = *(const float4*)&h[(unsigned)(n0 + row) * 128 + c4];
  }
  __syncthreads();

  int wave = t >> 6, lane = t & 63;
  int ich = wave & 3;            // i quarter: ic 4*ich .. 4*ich+3
  int oh  = wave >> 2;           // o half
  int o   = oh * 64 + lane;

  f32x2 accv[8];
#pragma unroll
  for (int n = 0; n < 8; ++n) accv[n] = (f32x2){0.f, 0.f};

  const float4* pq = (const float4*)PQT + o;   // + (ic*8+part)*128

  for (int ic = ich * 4; ic < ich * 4 + 4; ++ic) {
    const float4* pp = pq + (unsigned)ic * 1024;
    float4 r0 = pp[0],   r1 = pp[128], r2 = pp[256], r3 = pp[384],
           r4 = pp[512], r5 = pp[640], r6 = pp[768], r7 = pp[896];
    f32x2 A2[4] = {{r0.x, r0.y}, {r0.z, r0.w}, {r1.x, r1.y}, {r1.z, r1.w}};
    f32x2 B2[4] = {{r2.x, r2.y}, {r2.z, r2.w}, {r3.x, r3.y}, {r3.z, r3.w}};
    f32x2 P2[4] = {{r4.x, r4.y}, {r4.z, r4.w}, {r5.x, r5.y}, {r5.z, r5.w}};
    f32x2 D2[4] = {{r6.x, r6.y}, {r6.z, r6.w}, {r7.x, r7.y}, {r7.z, r7.w}};
    int i0 = ic * 8;
#pragma unroll
    for (int n = 0; n < 8; ++n) {
      float4 h0 = *(const float4*)&hsm[n][i0];           // broadcast ds_read
      float4 h1 = *(const float4*)&hsm[n][i0 + 4];
      f32x2 hh[4] = {{h0.x, h0.y}, {h0.z, h0.w}, {h1.x, h1.y}, {h1.z, h1.w}};
      f32x2 a2 = accv[n];
#pragma unroll
      for (int q = 0; q < 4; ++q) {
        f32x2 h2 = hh[q];
        unsigned hz = __float_as_uint(h2.x) | __float_as_uint(h2.y);
        if (__builtin_amdgcn_readfirstlane(hz) == 0) {
          a2 = a2 + D2[q];                 // h==0: contribution is exactly D'
        } else {
          f32x2 t2 = A2[q] * h2 + B2[q];   // v_pk_fma_f32
          f32x2 u2 = t2 * h2;              // v_pk_mul_f32
          f32x2 e2;
          e2.x = __builtin_amdgcn_exp2f(u2.x);
          e2.y = __builtin_amdgcn_exp2f(u2.y);
          f32x2 v2 = P2[q] * h2 + D2[q];   // v_pk_fma_f32
          a2 = v2 * e2 + a2;               // v_pk_fma_f32
        }
      }
      accv[n] = a2;
    }
  }

  // reduce i-quarters: ich 1..3 publish; barrier; ich 0 combines -> ksm.
  if (ich) {
#pragma unroll
    for (int n = 0; n < 8; ++n)
      red[ich - 1][oh][n][lane] = accv[n].x + accv[n].y;
  }
  __syncthreads();
  if (!ich) {
#pragma unroll
    for (int n = 0; n < 8; ++n) {
      ksm[n][o] = (accv[n].x + accv[n].y) + red[0][oh][n][lane] +
                  red[1][oh][n][lane] + red[2][oh][n][lane];
    }
  }
  // silu(h) in place (all hsm reads completed before the barrier above)
  if (t < 256) {
    int n = t >> 5, c4 = (t & 31) * 4;
    float4 v = *(float4*)&hsm[n][c4];
    float4 s;
    s.x = v.x * __builtin_amdgcn_rcpf(1.f + __builtin_amdgcn_exp2f(-LOG2E * v.x));
    s.y = v.y * __builtin_amdgcn_rcpf(1.f + __builtin_amdgcn_exp2f(-LOG2E * v.y));
    s.z = v.z * __builtin_amdgcn_rcpf(1.f + __builtin_amdgcn_exp2f(-LOG2E * v.z));
    s.w = v.w * __builtin_amdgcn_rcpf(1.f + __builtin_amdgcn_exp2f(-LOG2E * v.w));
    *(float4*)&hsm[n][c4] = s;
  }
  __syncthreads();

  // conv2 tail: 168 threads, thread (g,n): out[bb][g][sp] over K=[ksm|silu h]
  if (t < 168) {
    int n = t & 7, g = t >> 3;
    const float* w0 = w2c + g * 256;
    const float* kr = &ksm[n][0];
    const float* hr = &hsm[n][0];
    float a0 = 0.f;
#pragma unroll 4
    for (int k4 = 0; k4 < 32; ++k4) {
      float4 kv = *(const float4*)&kr[k4 * 4];
      float4 w = *(const float4*)&w0[k4 * 4];
      a0 += kv.x * w.x + kv.y * w.y + kv.z * w.z + kv.w * w.w;
    }
#pragma unroll 4
    for (int k4 = 0; k4 < 32; ++k4) {
      float4 hv = *(const float4*)&hr[k4 * 4];
      float4 w = *(const float4*)&w0[128 + k4 * 4];
      a0 += hv.x * w.x + hv.y * w.y + hv.z * w.z + hv.w * w.w;
    }
    int gn = n0 + n, bb = gn >> 12, sp = gn & 4095;
    out[(unsigned)(bb * 21 + g) * 4096 + sp] = a0 + b2[g];
  }
}

// ---------------- launch ---------------------------------------------------
extern "C" void kernel_launch(void* const* d_in, const int* in_sizes, int n_in,
                              void* d_out, int out_size, void* d_ws, size_t ws_size,
                              hipStream_t stream) {
  const float* x  = (const float*)d_in[0];
  const float* w1 = (const float*)d_in[1];
  const float* b1 = (const float*)d_in[2];
  const float* ks = (const float*)d_in[3];
  const float* kt = (const float*)d_in[4];
  const float* kw = (const float*)d_in[5];
  const float* kb = (const float*)d_in[6];
  const float* w2 = (const float*)d_in[7];
  const float* b2 = (const float*)d_in[8];
  float* out = (float*)d_out;
  float* ws  = (float*)d_ws;

  prep_all_k<<<2272, 256, 0, stream>>>(x, w1, ks, kt, kw, kb, w2, ws);
  conv1_mfma_k<<<256, 256, 0, stream>>>((const unsigned short*)(ws + OFF_XH),
                                        (const unsigned short*)(ws + OFF_WB),
                                        b1, ws + OFF_H);
  wavkan_conv2_k<<<2048, 512, 0, stream>>>(ws + OFF_H, ws + OFF_PQT,
                                           ws + OFF_W2, b2, out);
}

// Round 21
// 92.233 us; speedup vs baseline: 1.6978x; 1.6978x over previous
//
#include <hip/hip_runtime.h>
#include <math.h>

typedef __attribute__((ext_vector_type(8))) short s16x8;
typedef __attribute__((ext_vector_type(4))) float f32x4;
typedef __attribute__((ext_vector_type(2))) float f32x2;

#define LOG2E 1.4426950408889634f

// ---- workspace layout (float offsets) ----
#define OFF_XH   0           // xh bf16 NHWC [4][4096][256] = 2,097,152 floats
#define OFF_WB   2097152     // conv1 weights bf16 MFMA layout [ch2][ck8][tap9][g4][co64][j8]
#define OFF_PQT  2244608     // [ic16][part8][o128][4] = coalesced {A,B,P',D'}
#define OFF_W2   2310144     // W2cat [21][256] = [w2 | w2@base_w]
#define OFF_H    2315520     // h f32 NHWC [16384][128]

// ---------------- fused prologue: transpose x | prep weights | w2b ---------
__global__ __launch_bounds__(256) void prep_all_k(
    const float* __restrict__ x, const float* __restrict__ w1,
    const float* __restrict__ ks, const float* __restrict__ kt,
    const float* __restrict__ kw, const float* __restrict__ kb,
    const float* __restrict__ w2, float* __restrict__ ws) {
  int blk = blockIdx.x;
  int t = threadIdx.x;
  if (blk < 1024) {
    __shared__ float lsm[64][65];
    unsigned short* xh = (unsigned short*)(ws + OFF_XH);
    int pr = blk & 63, cib = (blk >> 6) & 3, bb = blk >> 8;
    int sp0 = pr * 64;
    const float* src = x + (unsigned)(bb * 256 + cib * 64) * 4096 + sp0;
#pragma unroll
    for (int rr = 0; rr < 16; ++rr) {
      int idx = rr * 256 + t;
      int ci = idx >> 6, px = idx & 63;
      lsm[ci][px] = src[ci * 4096 + px];
    }
    __syncthreads();
#pragma unroll
    for (int rr = 0; rr < 16; ++rr) {
      int idx = rr * 256 + t;
      int px = idx >> 6, ci = idx & 63;
      unsigned u = __float_as_uint(lsm[ci][px]);
      xh[(unsigned)(bb * 4096 + sp0 + px) * 256 + cib * 64 + ci] =
          (unsigned short)((u + 0x7FFF + ((u >> 16) & 1)) >> 16);
    }
  } else if (blk < 2251) {
    // KAN folding: contribution = fma(P',h,D') * exp2(h*fma(A,h,B));
    // A=Q, B=-2QT, P'=P0*2^C, D'=-P0*T*2^C, C=QT^2, Q=-0.5*log2e/s^2, P0=-kw/s.
    // Param layout coalesced: [ic][part8][o128][4f].
    int tid = (blk - 1024) * 256 + t;
    unsigned short* Wb = (unsigned short*)(ws + OFF_WB);
    if (tid < 294912) {
      int j = tid & 7, co = (tid >> 3) & 63, g = (tid >> 9) & 3, r = tid >> 11;
      int t9 = r % 9, q = r / 9, ck = q & 7, chh = q >> 3;
      int ci = ck * 32 + g * 8 + j, cog = chh * 64 + co;
      unsigned u = __float_as_uint(w1[(unsigned)(cog * 256 + ci) * 9 + t9]);
      Wb[tid] = (unsigned short)((u + 0x7FFF + ((u >> 16) & 1)) >> 16);
    } else if (tid < 294912 + 16384) {
      int i2 = tid - 294912;
      int i = i2 >> 7, o = i2 & 127;
      int ic = i >> 3, k = i & 7;
      float rs = 1.f / ks[o * 128 + i];
      float T  = kt[o * 128 + i];
      float A  = -0.7213475204444817f * rs * rs;   // Q
      float Bq = -2.f * A * T;
      float C  = A * T * T;
      float P0 = -rs * kw[o * 128 + i];
      float sc = exp2f(C);
      int khi = k >> 2, klo = k & 3;
      unsigned base = ((unsigned)ic * 8 * 128 + o) * 4 + klo;  // + part*512
      ws[OFF_PQT + base + (0 + khi) * 512] = A;
      ws[OFF_PQT + base + (2 + khi) * 512] = Bq;
      ws[OFF_PQT + base + (4 + khi) * 512] = P0 * sc;
      ws[OFF_PQT + base + (6 + khi) * 512] = -P0 * T * sc;
    } else if (tid < 294912 + 16384 + 2688) {
      int i3 = tid - 294912 - 16384;
      int nc = i3 >> 7, k = i3 & 127;
      ws[OFF_W2 + nc * 256 + k] = w2[nc * 128 + k];
    }
  } else {
    int nc = blk - 2251;
    if (t < 128) {
      float acc = 0.f;
      for (int o = 0; o < 128; ++o)
        acc = fmaf(w2[nc * 128 + o], kb[o * 128 + t], acc);
      ws[OFF_W2 + nc * 256 + 128 + t] = acc;
    }
  }
}

// ---------------- conv1 3x3 as bf16 MFMA implicit GEMM ---------------------
// Block 128M(2y x 64x) x 64N, Mr=4/Nr=2; explicit A+B double-buffer (116KB,
// 1 block/CU): issue ck+1 loads -> compute ck (72 MFMAs hide the loads) ->
// write buf^1 -> ONE barrier per ck. grid 256 = bb(4) x yt(32) x ch(2).
__global__ __launch_bounds__(256) void conv1_mfma_k(
    const unsigned short* __restrict__ xh, const unsigned short* __restrict__ Wb,
    const float* __restrict__ b1, float* __restrict__ h) {
  __shared__ unsigned short Asm[2][4 * 66 * 40];  // 2 x 21.1KB
  __shared__ unsigned short Bsm[2][18432];        // 2 x 36.9KB  (total 116KB)
  int blk = blockIdx.x;
  int ch = blk & 1, yt = (blk >> 1) & 31, bb = blk >> 6;
  int y0 = yt * 2;
  int t = threadIdx.x;
  int wave = t >> 6, lane = t & 63;
  int wn = wave & 1, wm = wave >> 1;   // wm = output y-row within tile
  int l15 = lane & 15, lg = lane >> 4;

  if (t < 16) {  // zero x-halo columns in BOTH buffers (stay zero)
    int bf = t >> 3, r = (t >> 1) & 3, xl = (t & 1) * 65;
    float4 z = {0, 0, 0, 0};
    float4* p = (float4*)&Asm[bf][(r * 66 + xl) * 40];
    p[0] = z; p[1] = z; p[2] = z; p[3] = z; p[4] = z;
  }

  f32x4 acc[4][2];
  f32x4 zz = {0.f, 0.f, 0.f, 0.f};
#pragma unroll
  for (int f = 0; f < 4; ++f) { acc[f][0] = zz; acc[f][1] = zz; }

  int r_st = t >> 6, x_st = t & 63;    // 4 rows x 64 px staging map
  int gy = y0 - 1 + r_st;
  bool yok = (gy >= 0) & (gy < 64);
  const unsigned short* asrc = xh + (unsigned)(bb * 4096 + gy * 64 + x_st) * 256;
  int aoff = (r_st * 66 + x_st + 1) * 40;   // ELEMENT offset into Asm[buf]
  const unsigned short* bslab = Wb + ch * 8 * 18432;

  // prologue: stage ck 0 into buf 0
  float4 av0 = {0,0,0,0}, av1 = av0, av2 = av0, av3 = av0;
  float4 bv[9];
  if (yok) {
    const float4* s = (const float4*)(asrc);
    av0 = s[0]; av1 = s[1]; av2 = s[2]; av3 = s[3];
  }
  {
    const float4* s = (const float4*)(bslab);
#pragma unroll
    for (int j = 0; j < 9; ++j) bv[j] = s[j * 256 + t];
  }
  {
    float4* d = (float4*)&Asm[0][aoff];
    d[0] = av0; d[1] = av1; d[2] = av2; d[3] = av3;
    float4* db = (float4*)&Bsm[0][0];
#pragma unroll
    for (int j = 0; j < 9; ++j) db[j * 256 + t] = bv[j];
  }
  __syncthreads();

  for (int ck = 0; ck < 8; ++ck) {
    int cur = ck & 1;
    // issue next chunk's loads (latency hides under compute below)
    if (ck < 7) {
      av0 = (float4){0,0,0,0}; av1 = av0; av2 = av0; av3 = av0;
      if (yok) {
        const float4* s = (const float4*)(asrc + (ck + 1) * 32);
        av0 = s[0]; av1 = s[1]; av2 = s[2]; av3 = s[3];
      }
      const float4* s = (const float4*)(bslab + (ck + 1) * 18432);
#pragma unroll
      for (int j = 0; j < 9; ++j) bv[j] = s[j * 256 + t];
    }
    // compute ck from buf[cur]
    const unsigned short* As = &Asm[cur][0];
    const unsigned short* Bs = &Bsm[cur][0];
#pragma unroll
    for (int t9 = 0; t9 < 9; ++t9) {
      int ky = t9 / 3, kx = t9 % 3;
      s16x8 a[4], b[2];
      int abase = ((wm + ky) * 66 + l15 + kx) * 40 + lg * 8;
#pragma unroll
      for (int f = 0; f < 4; ++f)
        a[f] = *(const s16x8*)&As[abase + f * 640];
#pragma unroll
      for (int n = 0; n < 2; ++n)
        b[n] = *(const s16x8*)&Bs[((t9 * 4 + lg) * 64 + wn * 32 + n * 16 + l15) * 8];
#pragma unroll
      for (int f = 0; f < 4; ++f)
#pragma unroll
        for (int n = 0; n < 2; ++n)
          acc[f][n] = __builtin_amdgcn_mfma_f32_16x16x32_bf16(a[f], b[n], acc[f][n], 0, 0, 0);
    }
    // write next chunk into the other buffer
    if (ck < 7) {
      float4* d = (float4*)&Asm[cur ^ 1][aoff];
      d[0] = av0; d[1] = av1; d[2] = av2; d[3] = av3;
      float4* db = (float4*)&Bsm[cur ^ 1][0];
#pragma unroll
      for (int j = 0; j < 9; ++j) db[j * 256 + t] = bv[j];
    }
    __syncthreads();
  }
  // epilogue: bias + relu, store h NHWC f32
#pragma unroll
  for (int n = 0; n < 2; ++n) {
    int co = ch * 64 + wn * 32 + n * 16 + l15;
    float bz = b1[co];
#pragma unroll
    for (int f = 0; f < 4; ++f) {
      int xbase = f * 16 + lg * 4;
      float* dst = h + (unsigned)(bb * 4096 + (y0 + wm) * 64 + xbase) * 128 + co;
#pragma unroll
      for (int r = 0; r < 4; ++r) {
        float v = acc[f][n][r] + bz;
        dst[r * 128] = v > 0.f ? v : 0.f;
      }
    }
  }
}

// ---------------- Wav-KAN + fused conv2 (r17 proven version) ---------------
// r21: zero-skip REVERTED — r20's wave-uniform branch inside the unrolled
// body blew VGPR 36->128 and spilled 114MB to scratch (dur 53->124us).
// Straight-line body restored byte-for-byte from r17 (53.3us proven).
__global__ __launch_bounds__(512) void wavkan_conv2_k(
    const float* __restrict__ h, const float* __restrict__ PQT,
    const float* __restrict__ w2c, const float* __restrict__ b2,
    float* __restrict__ out) {
  __shared__ float hsm[8][132];        // 4.2 KB
  __shared__ float red[3][2][8][64];   // 12 KB partial sums [ich-1][oh][n][lane]
  __shared__ float ksm[8][132];        // 4.2 KB k_wav rows
  int n0 = blockIdx.x * 8;
  int t = threadIdx.x;
  if (t < 256) {
    int row = t >> 5, c4 = (t & 31) * 4;
    *(float4*)&hsm[row][c4] = *(const float4*)&h[(unsigned)(n0 + row) * 128 + c4];
  }
  __syncthreads();

  int wave = t >> 6, lane = t & 63;
  int ich = wave & 3;            // i quarter: ic 4*ich .. 4*ich+3
  int oh  = wave >> 2;           // o half
  int o   = oh * 64 + lane;

  f32x2 accv[8];
#pragma unroll
  for (int n = 0; n < 8; ++n) accv[n] = (f32x2){0.f, 0.f};

  const float4* pq = (const float4*)PQT + o;   // + (ic*8+part)*128

  for (int ic = ich * 4; ic < ich * 4 + 4; ++ic) {
    const float4* pp = pq + (unsigned)ic * 1024;
    float4 r0 = pp[0],   r1 = pp[128], r2 = pp[256], r3 = pp[384],
           r4 = pp[512], r5 = pp[640], r6 = pp[768], r7 = pp[896];
    f32x2 A2[4] = {{r0.x, r0.y}, {r0.z, r0.w}, {r1.x, r1.y}, {r1.z, r1.w}};
    f32x2 B2[4] = {{r2.x, r2.y}, {r2.z, r2.w}, {r3.x, r3.y}, {r3.z, r3.w}};
    f32x2 P2[4] = {{r4.x, r4.y}, {r4.z, r4.w}, {r5.x, r5.y}, {r5.z, r5.w}};
    f32x2 D2[4] = {{r6.x, r6.y}, {r6.z, r6.w}, {r7.x, r7.y}, {r7.z, r7.w}};
    int i0 = ic * 8;
#pragma unroll
    for (int n = 0; n < 8; ++n) {
      float4 h0 = *(const float4*)&hsm[n][i0];           // broadcast ds_read
      float4 h1 = *(const float4*)&hsm[n][i0 + 4];
      f32x2 hh[4] = {{h0.x, h0.y}, {h0.z, h0.w}, {h1.x, h1.y}, {h1.z, h1.w}};
      f32x2 a2 = accv[n];
#pragma unroll
      for (int q = 0; q < 4; ++q) {
        f32x2 h2 = hh[q];
        f32x2 t2 = A2[q] * h2 + B2[q];     // v_pk_fma_f32
        f32x2 u2 = t2 * h2;                // v_pk_mul_f32
        f32x2 e2;
        e2.x = __builtin_amdgcn_exp2f(u2.x);
        e2.y = __builtin_amdgcn_exp2f(u2.y);
        f32x2 v2 = P2[q] * h2 + D2[q];     // v_pk_fma_f32
        a2 = v2 * e2 + a2;                 // v_pk_fma_f32
      }
      accv[n] = a2;
    }
  }

  // reduce i-quarters: ich 1..3 publish; barrier; ich 0 combines -> ksm.
  if (ich) {
#pragma unroll
    for (int n = 0; n < 8; ++n)
      red[ich - 1][oh][n][lane] = accv[n].x + accv[n].y;
  }
  __syncthreads();
  if (!ich) {
#pragma unroll
    for (int n = 0; n < 8; ++n) {
      ksm[n][o] = (accv[n].x + accv[n].y) + red[0][oh][n][lane] +
                  red[1][oh][n][lane] + red[2][oh][n][lane];
    }
  }
  // silu(h) in place (all hsm reads completed before the barrier above)
  if (t < 256) {
    int n = t >> 5, c4 = (t & 31) * 4;
    float4 v = *(float4*)&hsm[n][c4];
    float4 s;
    s.x = v.x * __builtin_amdgcn_rcpf(1.f + __builtin_amdgcn_exp2f(-LOG2E * v.x));
    s.y = v.y * __builtin_amdgcn_rcpf(1.f + __builtin_amdgcn_exp2f(-LOG2E * v.y));
    s.z = v.z * __builtin_amdgcn_rcpf(1.f + __builtin_amdgcn_exp2f(-LOG2E * v.z));
    s.w = v.w * __builtin_amdgcn_rcpf(1.f + __builtin_amdgcn_exp2f(-LOG2E * v.w));
    *(float4*)&hsm[n][c4] = s;
  }
  __syncthreads();

  // conv2 tail: 168 threads, thread (g,n): out[bb][g][sp] over K=[ksm|silu h]
  if (t < 168) {
    int n = t & 7, g = t >> 3;
    const float* w0 = w2c + g * 256;
    const float* kr = &ksm[n][0];
    const float* hr = &hsm[n][0];
    float a0 = 0.f;
#pragma unroll 4
    for (int k4 = 0; k4 < 32; ++k4) {
      float4 kv = *(const float4*)&kr[k4 * 4];
      float4 w = *(const float4*)&w0[k4 * 4];
      a0 += kv.x * w.x + kv.y * w.y + kv.z * w.z + kv.w * w.w;
    }
#pragma unroll 4
    for (int k4 = 0; k4 < 32; ++k4) {
      float4 hv = *(const float4*)&hr[k4 * 4];
      float4 w = *(const float4*)&w0[128 + k4 * 4];
      a0 += hv.x * w.x + hv.y * w.y + hv.z * w.z + hv.w * w.w;
    }
    int gn = n0 + n, bb = gn >> 12, sp = gn & 4095;
    out[(unsigned)(bb * 21 + g) * 4096 + sp] = a0 + b2[g];
  }
}

// ---------------- launch ---------------------------------------------------
extern "C" void kernel_launch(void* const* d_in, const int* in_sizes, int n_in,
                              void* d_out, int out_size, void* d_ws, size_t ws_size,
                              hipStream_t stream) {
  const float* x  = (const float*)d_in[0];
  const float* w1 = (const float*)d_in[1];
  const float* b1 = (const float*)d_in[2];
  const float* ks = (const float*)d_in[3];
  const float* kt = (const float*)d_in[4];
  const float* kw = (const float*)d_in[5];
  const float* kb = (const float*)d_in[6];
  const float* w2 = (const float*)d_in[7];
  const float* b2 = (const float*)d_in[8];
  float* out = (float*)d_out;
  float* ws  = (float*)d_ws;

  prep_all_k<<<2272, 256, 0, stream>>>(x, w1, ks, kt, kw, kb, w2, ws);
  conv1_mfma_k<<<256, 256, 0, stream>>>((const unsigned short*)(ws + OFF_XH),
                                        (const unsigned short*)(ws + OFF_WB),
                                        b1, ws + OFF_H);
  wavkan_conv2_k<<<2048, 512, 0, stream>>>(ws + OFF_H, ws + OFF_PQT,
                                           ws + OFF_W2, b2, out);
}

// Round 22
// 82.448 us; speedup vs baseline: 1.8993x; 1.1187x over previous
//
#include <hip/hip_runtime.h>
#include <math.h>

typedef __attribute__((ext_vector_type(8))) short s16x8;
typedef __attribute__((ext_vector_type(4))) float f32x4;
typedef __attribute__((ext_vector_type(2))) float f32x2;

#define LOG2E 1.4426950408889634f

// ---- workspace layout (float offsets) ----
#define OFF_XH   0           // xh bf16 NHWC [4][4096][256] = 2,097,152 floats
#define OFF_WB   2097152     // conv1 weights bf16 MFMA layout [ch2][ck8][tap9][g4][co64][j8]
#define OFF_PQT  2244608     // [ic16][part8][o128][4] = coalesced {A,B,P',D'}
#define OFF_W2   2310144     // W2cat [21][256] = [w2 | w2@base_w]
#define OFF_H    2315520     // h f32 NHWC [16384][128]

// ---------------- fused prologue: transpose x | prep weights | w2b ---------
__global__ __launch_bounds__(256) void prep_all_k(
    const float* __restrict__ x, const float* __restrict__ w1,
    const float* __restrict__ ks, const float* __restrict__ kt,
    const float* __restrict__ kw, const float* __restrict__ kb,
    const float* __restrict__ w2, float* __restrict__ ws) {
  int blk = blockIdx.x;
  int t = threadIdx.x;
  if (blk < 1024) {
    __shared__ float lsm[64][65];
    unsigned short* xh = (unsigned short*)(ws + OFF_XH);
    int pr = blk & 63, cib = (blk >> 6) & 3, bb = blk >> 8;
    int sp0 = pr * 64;
    const float* src = x + (unsigned)(bb * 256 + cib * 64) * 4096 + sp0;
#pragma unroll
    for (int rr = 0; rr < 16; ++rr) {
      int idx = rr * 256 + t;
      int ci = idx >> 6, px = idx & 63;
      lsm[ci][px] = src[ci * 4096 + px];
    }
    __syncthreads();
#pragma unroll
    for (int rr = 0; rr < 16; ++rr) {
      int idx = rr * 256 + t;
      int px = idx >> 6, ci = idx & 63;
      unsigned u = __float_as_uint(lsm[ci][px]);
      xh[(unsigned)(bb * 4096 + sp0 + px) * 256 + cib * 64 + ci] =
          (unsigned short)((u + 0x7FFF + ((u >> 16) & 1)) >> 16);
    }
  } else if (blk < 2251) {
    // KAN folding: contribution = fma(P',h,D') * exp2(h*fma(A,h,B));
    // A=Q, B=-2QT, P'=P0*2^C, D'=-P0*T*2^C, C=QT^2, Q=-0.5*log2e/s^2, P0=-kw/s.
    // Param layout coalesced: [ic][part8][o128][4f].
    int tid = (blk - 1024) * 256 + t;
    unsigned short* Wb = (unsigned short*)(ws + OFF_WB);
    if (tid < 294912) {
      int j = tid & 7, co = (tid >> 3) & 63, g = (tid >> 9) & 3, r = tid >> 11;
      int t9 = r % 9, q = r / 9, ck = q & 7, chh = q >> 3;
      int ci = ck * 32 + g * 8 + j, cog = chh * 64 + co;
      unsigned u = __float_as_uint(w1[(unsigned)(cog * 256 + ci) * 9 + t9]);
      Wb[tid] = (unsigned short)((u + 0x7FFF + ((u >> 16) & 1)) >> 16);
    } else if (tid < 294912 + 16384) {
      int i2 = tid - 294912;
      int i = i2 >> 7, o = i2 & 127;
      int ic = i >> 3, k = i & 7;
      float rs = 1.f / ks[o * 128 + i];
      float T  = kt[o * 128 + i];
      float A  = -0.7213475204444817f * rs * rs;   // Q
      float Bq = -2.f * A * T;
      float C  = A * T * T;
      float P0 = -rs * kw[o * 128 + i];
      float sc = exp2f(C);
      int khi = k >> 2, klo = k & 3;
      unsigned base = ((unsigned)ic * 8 * 128 + o) * 4 + klo;  // + part*512
      ws[OFF_PQT + base + (0 + khi) * 512] = A;
      ws[OFF_PQT + base + (2 + khi) * 512] = Bq;
      ws[OFF_PQT + base + (4 + khi) * 512] = P0 * sc;
      ws[OFF_PQT + base + (6 + khi) * 512] = -P0 * T * sc;
    } else if (tid < 294912 + 16384 + 2688) {
      int i3 = tid - 294912 - 16384;
      int nc = i3 >> 7, k = i3 & 127;
      ws[OFF_W2 + nc * 256 + k] = w2[nc * 128 + k];
    }
  } else {
    int nc = blk - 2251;
    if (t < 128) {
      float acc = 0.f;
      for (int o = 0; o < 128; ++o)
        acc = fmaf(w2[nc * 128 + o], kb[o * 128 + t], acc);
      ws[OFF_W2 + nc * 256 + 128 + t] = acc;
    }
  }
}

// ---------------- conv1 3x3 as bf16 MFMA implicit GEMM ---------------------
// r22 = exact r18 conv1 (best measured: 82.6us total), single-buffered.
// Ledger: r16/17 shape (64M, grid 512) -> 84.6; r18 (128M, grid 256, sbuf)
// -> 82.6; r21 explicit dbuf -> 92.2 (52 live VGPRs of staging serialized
// vmcnt waits at 1 wave/SIMD — reverted). Only change vs r18: drop the
// ",2" launch bound (grid 256 = 1 block/CU can never reach 2 waves/SIMD;
// the cap only constrained the register allocator).
__global__ __launch_bounds__(256) void conv1_mfma_k(
    const unsigned short* __restrict__ xh, const unsigned short* __restrict__ Wb,
    const float* __restrict__ b1, float* __restrict__ h) {
  __shared__ unsigned short Asm[4 * 66 * 40];  // [yrow4][x66][ci 32 pad40] 21.1KB
  __shared__ unsigned short Bsm[18432];        // [tap9][g4][co64][j8]      36.9KB
  int blk = blockIdx.x;
  int ch = blk & 1, yt = (blk >> 1) & 31, bb = blk >> 6;
  int y0 = yt * 2;
  int t = threadIdx.x;
  int wave = t >> 6, lane = t & 63;
  int wn = wave & 1, wm = wave >> 1;   // wm = output y-row within tile
  int l15 = lane & 15, lg = lane >> 4;

  if (t < 8) {  // zero x-halo columns (always OOB; stay zero across chunks)
    int r = t >> 1, xl = (t & 1) * 65;
    float4 z = {0, 0, 0, 0};
    float4* p = (float4*)&Asm[(r * 66 + xl) * 40];
    p[0] = z; p[1] = z; p[2] = z; p[3] = z; p[4] = z;
  }

  f32x4 acc[4][2];
  f32x4 zz = {0.f, 0.f, 0.f, 0.f};
#pragma unroll
  for (int f = 0; f < 4; ++f) { acc[f][0] = zz; acc[f][1] = zz; }

  int r_st = t >> 6, x_st = t & 63;    // 4 rows x 64 px staging map
  int gy = y0 - 1 + r_st;
  bool yok = (gy >= 0) & (gy < 64);
  const unsigned short* asrc = xh + (unsigned)(bb * 4096 + gy * 64 + x_st) * 256;
  unsigned short* adst = &Asm[(r_st * 66 + x_st + 1) * 40];
  const unsigned short* bslab = Wb + ch * 8 * 18432;

  for (int ck = 0; ck < 8; ++ck) {
    float4 v0 = {0, 0, 0, 0}, v1 = v0, v2 = v0, v3 = v0;
    if (yok) {
      const float4* s = (const float4*)(asrc + ck * 32);
      v0 = s[0]; v1 = s[1]; v2 = s[2]; v3 = s[3];
    }
    { float4* d = (float4*)adst; d[0] = v0; d[1] = v1; d[2] = v2; d[3] = v3; }
    {
      const float4* s = (const float4*)(bslab + ck * 18432);
      float4* d = (float4*)Bsm;
#pragma unroll
      for (int j = 0; j < 9; ++j) d[j * 256 + t] = s[j * 256 + t];
    }
    __syncthreads();
#pragma unroll
    for (int t9 = 0; t9 < 9; ++t9) {
      int ky = t9 / 3, kx = t9 % 3;
      s16x8 a[4], b[2];
      int abase = ((wm + ky) * 66 + l15 + kx) * 40 + lg * 8;
#pragma unroll
      for (int f = 0; f < 4; ++f)
        a[f] = *(const s16x8*)&Asm[abase + f * 640];
#pragma unroll
      for (int n = 0; n < 2; ++n)
        b[n] = *(const s16x8*)&Bsm[((t9 * 4 + lg) * 64 + wn * 32 + n * 16 + l15) * 8];
#pragma unroll
      for (int f = 0; f < 4; ++f)
#pragma unroll
        for (int n = 0; n < 2; ++n)
          acc[f][n] = __builtin_amdgcn_mfma_f32_16x16x32_bf16(a[f], b[n], acc[f][n], 0, 0, 0);
    }
    __syncthreads();
  }
  // epilogue: bias + relu, store h NHWC f32
#pragma unroll
  for (int n = 0; n < 2; ++n) {
    int co = ch * 64 + wn * 32 + n * 16 + l15;
    float bz = b1[co];
#pragma unroll
    for (int f = 0; f < 4; ++f) {
      int xbase = f * 16 + lg * 4;
      float* dst = h + (unsigned)(bb * 4096 + (y0 + wm) * 64 + xbase) * 128 + co;
#pragma unroll
      for (int r = 0; r < 4; ++r) {
        float v = acc[f][n][r] + bz;
        dst[r * 128] = v > 0.f ? v : 0.f;
      }
    }
  }
}

// ---------------- Wav-KAN + fused conv2 (r17 proven version) ---------------
// Straight-line body (r20's zero-skip branch blew VGPR 36->128, 114MB of
// scratch spills — never branch inside this unrolled body).
__global__ __launch_bounds__(512) void wavkan_conv2_k(
    const float* __restrict__ h, const float* __restrict__ PQT,
    const float* __restrict__ w2c, const float* __restrict__ b2,
    float* __restrict__ out) {
  __shared__ float hsm[8][132];        // 4.2 KB
  __shared__ float red[3][2][8][64];   // 12 KB partial sums [ich-1][oh][n][lane]
  __shared__ float ksm[8][132];        // 4.2 KB k_wav rows
  int n0 = blockIdx.x * 8;
  int t = threadIdx.x;
  if (t < 256) {
    int row = t >> 5, c4 = (t & 31) * 4;
    *(float4*)&hsm[row][c4] = *(const float4*)&h[(unsigned)(n0 + row) * 128 + c4];
  }
  __syncthreads();

  int wave = t >> 6, lane = t & 63;
  int ich = wave & 3;            // i quarter: ic 4*ich .. 4*ich+3
  int oh  = wave >> 2;           // o half
  int o   = oh * 64 + lane;

  f32x2 accv[8];
#pragma unroll
  for (int n = 0; n < 8; ++n) accv[n] = (f32x2){0.f, 0.f};

  const float4* pq = (const float4*)PQT + o;   // + (ic*8+part)*128

  for (int ic = ich * 4; ic < ich * 4 + 4; ++ic) {
    const float4* pp = pq + (unsigned)ic * 1024;
    float4 r0 = pp[0],   r1 = pp[128], r2 = pp[256], r3 = pp[384],
           r4 = pp[512], r5 = pp[640], r6 = pp[768], r7 = pp[896];
    f32x2 A2[4] = {{r0.x, r0.y}, {r0.z, r0.w}, {r1.x, r1.y}, {r1.z, r1.w}};
    f32x2 B2[4] = {{r2.x, r2.y}, {r2.z, r2.w}, {r3.x, r3.y}, {r3.z, r3.w}};
    f32x2 P2[4] = {{r4.x, r4.y}, {r4.z, r4.w}, {r5.x, r5.y}, {r5.z, r5.w}};
    f32x2 D2[4] = {{r6.x, r6.y}, {r6.z, r6.w}, {r7.x, r7.y}, {r7.z, r7.w}};
    int i0 = ic * 8;
#pragma unroll
    for (int n = 0; n < 8; ++n) {
      float4 h0 = *(const float4*)&hsm[n][i0];           // broadcast ds_read
      float4 h1 = *(const float4*)&hsm[n][i0 + 4];
      f32x2 hh[4] = {{h0.x, h0.y}, {h0.z, h0.w}, {h1.x, h1.y}, {h1.z, h1.w}};
      f32x2 a2 = accv[n];
#pragma unroll
      for (int q = 0; q < 4; ++q) {
        f32x2 h2 = hh[q];
        f32x2 t2 = A2[q] * h2 + B2[q];     // v_pk_fma_f32
        f32x2 u2 = t2 * h2;                // v_pk_mul_f32
        f32x2 e2;
        e2.x = __builtin_amdgcn_exp2f(u2.x);
        e2.y = __builtin_amdgcn_exp2f(u2.y);
        f32x2 v2 = P2[q] * h2 + D2[q];     // v_pk_fma_f32
        a2 = v2 * e2 + a2;                 // v_pk_fma_f32
      }
      accv[n] = a2;
    }
  }

  // reduce i-quarters: ich 1..3 publish; barrier; ich 0 combines -> ksm.
  if (ich) {
#pragma unroll
    for (int n = 0; n < 8; ++n)
      red[ich - 1][oh][n][lane] = accv[n].x + accv[n].y;
  }
  __syncthreads();
  if (!ich) {
#pragma unroll
    for (int n = 0; n < 8; ++n) {
      ksm[n][o] = (accv[n].x + accv[n].y) + red[0][oh][n][lane] +
                  red[1][oh][n][lane] + red[2][oh][n][lane];
    }
  }
  // silu(h) in place (all hsm reads completed before the barrier above)
  if (t < 256) {
    int n = t >> 5, c4 = (t & 31) * 4;
    float4 v = *(float4*)&hsm[n][c4];
    float4 s;
    s.x = v.x * __builtin_amdgcn_rcpf(1.f + __builtin_amdgcn_exp2f(-LOG2E * v.x));
    s.y = v.y * __builtin_amdgcn_rcpf(1.f + __builtin_amdgcn_exp2f(-LOG2E * v.y));
    s.z = v.z * __builtin_amdgcn_rcpf(1.f + __builtin_amdgcn_exp2f(-LOG2E * v.z));
    s.w = v.w * __builtin_amdgcn_rcpf(1.f + __builtin_amdgcn_exp2f(-LOG2E * v.w));
    *(float4*)&hsm[n][c4] = s;
  }
  __syncthreads();

  // conv2 tail: 168 threads, thread (g,n): out[bb][g][sp] over K=[ksm|silu h]
  if (t < 168) {
    int n = t & 7, g = t >> 3;
    const float* w0 = w2c + g * 256;
    const float* kr = &ksm[n][0];
    const float* hr = &hsm[n][0];
    float a0 = 0.f;
#pragma unroll 4
    for (int k4 = 0; k4 < 32; ++k4) {
      float4 kv = *(const float4*)&kr[k4 * 4];
      float4 w = *(const float4*)&w0[k4 * 4];
      a0 += kv.x * w.x + kv.y * w.y + kv.z * w.z + kv.w * w.w;
    }
#pragma unroll 4
    for (int k4 = 0; k4 < 32; ++k4) {
      float4 hv = *(const float4*)&hr[k4 * 4];
      float4 w = *(const float4*)&w0[128 + k4 * 4];
      a0 += hv.x * w.x + hv.y * w.y + hv.z * w.z + hv.w * w.w;
    }
    int gn = n0 + n, bb = gn >> 12, sp = gn & 4095;
    out[(unsigned)(bb * 21 + g) * 4096 + sp] = a0 + b2[g];
  }
}

// ---------------- launch ---------------------------------------------------
extern "C" void kernel_launch(void* const* d_in, const int* in_sizes, int n_in,
                              void* d_out, int out_size, void* d_ws, size_t ws_size,
                              hipStream_t stream) {
  const float* x  = (const float*)d_in[0];
  const float* w1 = (const float*)d_in[1];
  const float* b1 = (const float*)d_in[2];
  const float* ks = (const float*)d_in[3];
  const float* kt = (const float*)d_in[4];
  const float* kw = (const float*)d_in[5];
  const float* kb = (const float*)d_in[6];
  const float* w2 = (const float*)d_in[7];
  const float* b2 = (const float*)d_in[8];
  float* out = (float*)d_out;
  float* ws  = (float*)d_ws;

  prep_all_k<<<2272, 256, 0, stream>>>(x, w1, ks, kt, kw, kb, w2, ws);
  conv1_mfma_k<<<256, 256, 0, stream>>>((const unsigned short*)(ws + OFF_XH),
                                        (const unsigned short*)(ws + OFF_WB),
                                        b1, ws + OFF_H);
  wavkan_conv2_k<<<2048, 512, 0, stream>>>(ws + OFF_H, ws + OFF_PQT,
                                           ws + OFF_W2, b2, out);
}

// Round 23
// 82.364 us; speedup vs baseline: 1.9013x; 1.0010x over previous
//
#include <hip/hip_runtime.h>
#include <math.h>

typedef __attribute__((ext_vector_type(8))) short s16x8;
typedef __attribute__((ext_vector_type(4))) float f32x4;
typedef __attribute__((ext_vector_type(2))) float f32x2;

#define LOG2E 1.4426950408889634f

// ---- workspace layout (float offsets) ----
#define OFF_XH   0           // xh bf16 NHWC [4][4096][256] = 2,097,152 floats
#define OFF_WB   2097152     // conv1 weights bf16 MFMA layout [ch2][ck8][tap9][g4][co64][j8]
#define OFF_PQT  2244608     // [ic16][part8][o128][4] = coalesced {A,B,P',D'}
#define OFF_W2   2310144     // W2cat [21][256] = [w2 | w2@base_w]
#define OFF_H    2315520     // h f32 NHWC [16384][128]

// ---------------- fused prologue: transpose x | prep weights | w2b ---------
__global__ __launch_bounds__(256) void prep_all_k(
    const float* __restrict__ x, const float* __restrict__ w1,
    const float* __restrict__ ks, const float* __restrict__ kt,
    const float* __restrict__ kw, const float* __restrict__ kb,
    const float* __restrict__ w2, float* __restrict__ ws) {
  int blk = blockIdx.x;
  int t = threadIdx.x;
  if (blk < 1024) {
    __shared__ float lsm[64][65];
    unsigned short* xh = (unsigned short*)(ws + OFF_XH);
    int pr = blk & 63, cib = (blk >> 6) & 3, bb = blk >> 8;
    int sp0 = pr * 64;
    const float* src = x + (unsigned)(bb * 256 + cib * 64) * 4096 + sp0;
#pragma unroll
    for (int rr = 0; rr < 16; ++rr) {
      int idx = rr * 256 + t;
      int ci = idx >> 6, px = idx & 63;
      lsm[ci][px] = src[ci * 4096 + px];
    }
    __syncthreads();
#pragma unroll
    for (int rr = 0; rr < 16; ++rr) {
      int idx = rr * 256 + t;
      int px = idx >> 6, ci = idx & 63;
      unsigned u = __float_as_uint(lsm[ci][px]);
      xh[(unsigned)(bb * 4096 + sp0 + px) * 256 + cib * 64 + ci] =
          (unsigned short)((u + 0x7FFF + ((u >> 16) & 1)) >> 16);
    }
  } else if (blk < 2251) {
    // KAN folding: contribution = fma(P',h,D') * exp2(h*fma(A,h,B));
    // A=Q, B=-2QT, P'=P0*2^C, D'=-P0*T*2^C, C=QT^2, Q=-0.5*log2e/s^2, P0=-kw/s.
    // Param layout coalesced: [ic][part8][o128][4f].
    int tid = (blk - 1024) * 256 + t;
    unsigned short* Wb = (unsigned short*)(ws + OFF_WB);
    if (tid < 294912) {
      int j = tid & 7, co = (tid >> 3) & 63, g = (tid >> 9) & 3, r = tid >> 11;
      int t9 = r % 9, q = r / 9, ck = q & 7, chh = q >> 3;
      int ci = ck * 32 + g * 8 + j, cog = chh * 64 + co;
      unsigned u = __float_as_uint(w1[(unsigned)(cog * 256 + ci) * 9 + t9]);
      Wb[tid] = (unsigned short)((u + 0x7FFF + ((u >> 16) & 1)) >> 16);
    } else if (tid < 294912 + 16384) {
      int i2 = tid - 294912;
      int i = i2 >> 7, o = i2 & 127;
      int ic = i >> 3, k = i & 7;
      float rs = 1.f / ks[o * 128 + i];
      float T  = kt[o * 128 + i];
      float A  = -0.7213475204444817f * rs * rs;   // Q
      float Bq = -2.f * A * T;
      float C  = A * T * T;
      float P0 = -rs * kw[o * 128 + i];
      float sc = exp2f(C);
      int khi = k >> 2, klo = k & 3;
      unsigned base = ((unsigned)ic * 8 * 128 + o) * 4 + klo;  // + part*512
      ws[OFF_PQT + base + (0 + khi) * 512] = A;
      ws[OFF_PQT + base + (2 + khi) * 512] = Bq;
      ws[OFF_PQT + base + (4 + khi) * 512] = P0 * sc;
      ws[OFF_PQT + base + (6 + khi) * 512] = -P0 * T * sc;
    } else if (tid < 294912 + 16384 + 2688) {
      int i3 = tid - 294912 - 16384;
      int nc = i3 >> 7, k = i3 & 127;
      ws[OFF_W2 + nc * 256 + k] = w2[nc * 128 + k];
    }
  } else {
    int nc = blk - 2251;
    if (t < 128) {
      float acc = 0.f;
      for (int o = 0; o < 128; ++o)
        acc = fmaf(w2[nc * 128 + o], kb[o * 128 + t], acc);
      ws[OFF_W2 + nc * 256 + 128 + t] = acc;
    }
  }
}

// ---------------- conv1 3x3 as bf16 MFMA implicit GEMM ---------------------
// Banked best (r18/r22 ledger): 128M(2y x 64x) x 64N, Mr=4/Nr=2, single-
// buffered, grid 256. (dbuf r21: -10us regression; 64M grid 512: -2us.)
__global__ __launch_bounds__(256) void conv1_mfma_k(
    const unsigned short* __restrict__ xh, const unsigned short* __restrict__ Wb,
    const float* __restrict__ b1, float* __restrict__ h) {
  __shared__ unsigned short Asm[4 * 66 * 40];  // [yrow4][x66][ci 32 pad40] 21.1KB
  __shared__ unsigned short Bsm[18432];        // [tap9][g4][co64][j8]      36.9KB
  int blk = blockIdx.x;
  int ch = blk & 1, yt = (blk >> 1) & 31, bb = blk >> 6;
  int y0 = yt * 2;
  int t = threadIdx.x;
  int wave = t >> 6, lane = t & 63;
  int wn = wave & 1, wm = wave >> 1;   // wm = output y-row within tile
  int l15 = lane & 15, lg = lane >> 4;

  if (t < 8) {  // zero x-halo columns (always OOB; stay zero across chunks)
    int r = t >> 1, xl = (t & 1) * 65;
    float4 z = {0, 0, 0, 0};
    float4* p = (float4*)&Asm[(r * 66 + xl) * 40];
    p[0] = z; p[1] = z; p[2] = z; p[3] = z; p[4] = z;
  }

  f32x4 acc[4][2];
  f32x4 zz = {0.f, 0.f, 0.f, 0.f};
#pragma unroll
  for (int f = 0; f < 4; ++f) { acc[f][0] = zz; acc[f][1] = zz; }

  int r_st = t >> 6, x_st = t & 63;    // 4 rows x 64 px staging map
  int gy = y0 - 1 + r_st;
  bool yok = (gy >= 0) & (gy < 64);
  const unsigned short* asrc = xh + (unsigned)(bb * 4096 + gy * 64 + x_st) * 256;
  unsigned short* adst = &Asm[(r_st * 66 + x_st + 1) * 40];
  const unsigned short* bslab = Wb + ch * 8 * 18432;

  for (int ck = 0; ck < 8; ++ck) {
    float4 v0 = {0, 0, 0, 0}, v1 = v0, v2 = v0, v3 = v0;
    if (yok) {
      const float4* s = (const float4*)(asrc + ck * 32);
      v0 = s[0]; v1 = s[1]; v2 = s[2]; v3 = s[3];
    }
    { float4* d = (float4*)adst; d[0] = v0; d[1] = v1; d[2] = v2; d[3] = v3; }
    {
      const float4* s = (const float4*)(bslab + ck * 18432);
      float4* d = (float4*)Bsm;
#pragma unroll
      for (int j = 0; j < 9; ++j) d[j * 256 + t] = s[j * 256 + t];
    }
    __syncthreads();
#pragma unroll
    for (int t9 = 0; t9 < 9; ++t9) {
      int ky = t9 / 3, kx = t9 % 3;
      s16x8 a[4], b[2];
      int abase = ((wm + ky) * 66 + l15 + kx) * 40 + lg * 8;
#pragma unroll
      for (int f = 0; f < 4; ++f)
        a[f] = *(const s16x8*)&Asm[abase + f * 640];
#pragma unroll
      for (int n = 0; n < 2; ++n)
        b[n] = *(const s16x8*)&Bsm[((t9 * 4 + lg) * 64 + wn * 32 + n * 16 + l15) * 8];
#pragma unroll
      for (int f = 0; f < 4; ++f)
#pragma unroll
        for (int n = 0; n < 2; ++n)
          acc[f][n] = __builtin_amdgcn_mfma_f32_16x16x32_bf16(a[f], b[n], acc[f][n], 0, 0, 0);
    }
    __syncthreads();
  }
  // epilogue: bias + relu, store h NHWC f32
#pragma unroll
  for (int n = 0; n < 2; ++n) {
    int co = ch * 64 + wn * 32 + n * 16 + l15;
    float bz = b1[co];
#pragma unroll
    for (int f = 0; f < 4; ++f) {
      int xbase = f * 16 + lg * 4;
      float* dst = h + (unsigned)(bb * 4096 + (y0 + wm) * 64 + xbase) * 128 + co;
#pragma unroll
      for (int r = 0; r < 4; ++r) {
        float v = acc[f][n][r] + bz;
        dst[r * 128] = v > 0.f ? v : 0.f;
      }
    }
  }
}

// ---------------- Wav-KAN + fused conv2 ------------------------------------
// r23 experiment: __launch_bounds__(512, 4). The compiler self-throttled to
// VGPR=36 (targeting 8 waves/SIMD), but the inner loop's natural live set
// (16 param f32x2 + 8 acc f32x2 + hh) is ~60+ regs — at 36 it must remat/
// serialize, matching the stubborn ~37% issue-idle. Measured occupancy is
// extrinsically capped ~45% (3.6 waves/SIMD), so up to 128 VGPR (4 waves/
// SIMD) is free. Straight-line body unchanged (r20 lesson: no branches).
__global__ __launch_bounds__(512, 4) void wavkan_conv2_k(
    const float* __restrict__ h, const float* __restrict__ PQT,
    const float* __restrict__ w2c, const float* __restrict__ b2,
    float* __restrict__ out) {
  __shared__ float hsm[8][132];        // 4.2 KB
  __shared__ float red[3][2][8][64];   // 12 KB partial sums [ich-1][oh][n][lane]
  __shared__ float ksm[8][132];        // 4.2 KB k_wav rows
  int n0 = blockIdx.x * 8;
  int t = threadIdx.x;
  if (t < 256) {
    int row = t >> 5, c4 = (t & 31) * 4;
    *(float4*)&hsm[row][c4] = *(const float4*)&h[(unsigned)(n0 + row) * 128 + c4];
  }
  __syncthreads();

  int wave = t >> 6, lane = t & 63;
  int ich = wave & 3;            // i quarter: ic 4*ich .. 4*ich+3
  int oh  = wave >> 2;           // o half
  int o   = oh * 64 + lane;

  f32x2 accv[8];
#pragma unroll
  for (int n = 0; n < 8; ++n) accv[n] = (f32x2){0.f, 0.f};

  const float4* pq = (const float4*)PQT + o;   // + (ic*8+part)*128

  for (int ic = ich * 4; ic < ich * 4 + 4; ++ic) {
    const float4* pp = pq + (unsigned)ic * 1024;
    float4 r0 = pp[0],   r1 = pp[128], r2 = pp[256], r3 = pp[384],
           r4 = pp[512], r5 = pp[640], r6 = pp[768], r7 = pp[896];
    f32x2 A2[4] = {{r0.x, r0.y}, {r0.z, r0.w}, {r1.x, r1.y}, {r1.z, r1.w}};
    f32x2 B2[4] = {{r2.x, r2.y}, {r2.z, r2.w}, {r3.x, r3.y}, {r3.z, r3.w}};
    f32x2 P2[4] = {{r4.x, r4.y}, {r4.z, r4.w}, {r5.x, r5.y}, {r5.z, r5.w}};
    f32x2 D2[4] = {{r6.x, r6.y}, {r6.z, r6.w}, {r7.x, r7.y}, {r7.z, r7.w}};
    int i0 = ic * 8;
#pragma unroll
    for (int n = 0; n < 8; ++n) {
      float4 h0 = *(const float4*)&hsm[n][i0];           // broadcast ds_read
      float4 h1 = *(const float4*)&hsm[n][i0 + 4];
      f32x2 hh[4] = {{h0.x, h0.y}, {h0.z, h0.w}, {h1.x, h1.y}, {h1.z, h1.w}};
      f32x2 a2 = accv[n];
#pragma unroll
      for (int q = 0; q < 4; ++q) {
        f32x2 h2 = hh[q];
        f32x2 t2 = A2[q] * h2 + B2[q];     // v_pk_fma_f32
        f32x2 u2 = t2 * h2;                // v_pk_mul_f32
        f32x2 e2;
        e2.x = __builtin_amdgcn_exp2f(u2.x);
        e2.y = __builtin_amdgcn_exp2f(u2.y);
        f32x2 v2 = P2[q] * h2 + D2[q];     // v_pk_fma_f32
        a2 = v2 * e2 + a2;                 // v_pk_fma_f32
      }
      accv[n] = a2;
    }
  }

  // reduce i-quarters: ich 1..3 publish; barrier; ich 0 combines -> ksm.
  if (ich) {
#pragma unroll
    for (int n = 0; n < 8; ++n)
      red[ich - 1][oh][n][lane] = accv[n].x + accv[n].y;
  }
  __syncthreads();
  if (!ich) {
#pragma unroll
    for (int n = 0; n < 8; ++n) {
      ksm[n][o] = (accv[n].x + accv[n].y) + red[0][oh][n][lane] +
                  red[1][oh][n][lane] + red[2][oh][n][lane];
    }
  }
  // silu(h) in place (all hsm reads completed before the barrier above)
  if (t < 256) {
    int n = t >> 5, c4 = (t & 31) * 4;
    float4 v = *(float4*)&hsm[n][c4];
    float4 s;
    s.x = v.x * __builtin_amdgcn_rcpf(1.f + __builtin_amdgcn_exp2f(-LOG2E * v.x));
    s.y = v.y * __builtin_amdgcn_rcpf(1.f + __builtin_amdgcn_exp2f(-LOG2E * v.y));
    s.z = v.z * __builtin_amdgcn_rcpf(1.f + __builtin_amdgcn_exp2f(-LOG2E * v.z));
    s.w = v.w * __builtin_amdgcn_rcpf(1.f + __builtin_amdgcn_exp2f(-LOG2E * v.w));
    *(float4*)&hsm[n][c4] = s;
  }
  __syncthreads();

  // conv2 tail: 168 threads, thread (g,n): out[bb][g][sp] over K=[ksm|silu h]
  if (t < 168) {
    int n = t & 7, g = t >> 3;
    const float* w0 = w2c + g * 256;
    const float* kr = &ksm[n][0];
    const float* hr = &hsm[n][0];
    float a0 = 0.f;
#pragma unroll 4
    for (int k4 = 0; k4 < 32; ++k4) {
      float4 kv = *(const float4*)&kr[k4 * 4];
      float4 w = *(const float4*)&w0[k4 * 4];
      a0 += kv.x * w.x + kv.y * w.y + kv.z * w.z + kv.w * w.w;
    }
#pragma unroll 4
    for (int k4 = 0; k4 < 32; ++k4) {
      float4 hv = *(const float4*)&hr[k4 * 4];
      float4 w = *(const float4*)&w0[128 + k4 * 4];
      a0 += hv.x * w.x + hv.y * w.y + hv.z * w.z + hv.w * w.w;
    }
    int gn = n0 + n, bb = gn >> 12, sp = gn & 4095;
    out[(unsigned)(bb * 21 + g) * 4096 + sp] = a0 + b2[g];
  }
}

// ---------------- launch ---------------------------------------------------
extern "C" void kernel_launch(void* const* d_in, const int* in_sizes, int n_in,
                              void* d_out, int out_size, void* d_ws, size_t ws_size,
                              hipStream_t stream) {
  const float* x  = (const float*)d_in[0];
  const float* w1 = (const float*)d_in[1];
  const float* b1 = (const float*)d_in[2];
  const float* ks = (const float*)d_in[3];
  const float* kt = (const float*)d_in[4];
  const float* kw = (const float*)d_in[5];
  const float* kb = (const float*)d_in[6];
  const float* w2 = (const float*)d_in[7];
  const float* b2 = (const float*)d_in[8];
  float* out = (float*)d_out;
  float* ws  = (float*)d_ws;

  prep_all_k<<<2272, 256, 0, stream>>>(x, w1, ks, kt, kw, kb, w2, ws);
  conv1_mfma_k<<<256, 256, 0, stream>>>((const unsigned short*)(ws + OFF_XH),
                                        (const unsigned short*)(ws + OFF_WB),
                                        b1, ws + OFF_H);
  wavkan_conv2_k<<<2048, 512, 0, stream>>>(ws + OFF_H, ws + OFF_PQT,
                                           ws + OFF_W2, b2, out);
}